// Round 1
// baseline (97.971 us; speedup 1.0000x reference)
//
#include <hip/hip_runtime.h>

#define NF 40
#define ED 128
#define NB 1024
#define NIX 780
#define XROW (NF * ED)      // 5120
#define KROW (NIX * ED)     // 99840

typedef __attribute__((ext_vector_type(8))) short bf16x8;
typedef __attribute__((ext_vector_type(4))) float f32x4;
typedef __attribute__((ext_vector_type(4))) unsigned short ushx4;

__device__ __forceinline__ unsigned short f2bf(float x) {
  unsigned int u = __float_as_uint(x);
  u = (u + 0x7FFFu + ((u >> 16) & 1u)) >> 16;
  return (unsigned short)u;
}
__device__ __forceinline__ float bf2f(unsigned short h) {
  return __uint_as_float(((unsigned int)h) << 16);
}
// element-index swizzle for a [rows][128] bf16 tile: byte ^= ((row&7)<<4)
__device__ __forceinline__ int swz(int row, int col) {
  return row * 128 + (col ^ ((row & 7) << 3));
}

__launch_bounds__(256, 2)
__global__ void opn_kernel(const float* __restrict__ x,
                           const float* __restrict__ kern,
                           float* __restrict__ out) {
  __shared__ unsigned short Klds[128 * 128];  // K_n, swizzled bf16
  __shared__ unsigned short Plds[64 * 128];   // P b-tile, swizzled bf16
  __shared__ unsigned short Qlds[64 * 132];   // Q b-tile, padded bf16

  const int n = blockIdx.x;
  const int tid = threadIdx.x;
  const int lane = tid & 63;
  const int w = tid >> 6;
  const int lm = lane & 15;
  const int lq = lane >> 4;

  // pair (fi, fj) from linear index n
  int fi = 0, base = 0;
  while (base + (NF - 1 - fi) <= n) { base += NF - 1 - fi; ++fi; }
  const int fj = fi + 1 + (n - base);

  // ---- stage K_n into LDS (bf16, swizzled) ----
  {
    const int r8 = tid >> 5;          // 0..7
    const int d0 = (tid & 31) * 4;    // 0..124
    const float* kb = kern + (size_t)n * ED + d0;
    #pragma unroll
    for (int p = 0; p < 16; ++p) {
      int e = p * 8 + r8;
      float4 v = *reinterpret_cast<const float4*>(kb + (size_t)e * KROW);
      ushx4 h;
      h[0] = f2bf(v.x); h[1] = f2bf(v.y); h[2] = f2bf(v.z); h[3] = f2bf(v.w);
      *reinterpret_cast<ushx4*>(&Klds[swz(e, d0)]) = h;
    }
  }
  __syncthreads();

  // ---- hoist K into registers as MFMA B-operand fragments ----
  // B[k=d][col=e]: lane holds col=lm (+16*f), k = lq*8 + j (+32*kk)
  bf16x8 bfr[4][8];
  #pragma unroll
  for (int kk = 0; kk < 4; ++kk)
    #pragma unroll
    for (int f = 0; f < 8; ++f)
      bfr[kk][f] = *reinterpret_cast<const bf16x8*>(
          &Klds[swz(f * 16 + lm, kk * 32 + lq * 8)]);

  const int r8 = tid >> 5;
  const int c4 = (tid & 31) * 4;

  for (int t = 0; t < 8; ++t) {
    const int b0 = blockIdx.y * 512 + t * 64;
    __syncthreads();  // previous tile's readers done before overwrite
    #pragma unroll
    for (int p = 0; p < 8; ++p) {
      int r = p * 8 + r8;
      const float* xb = x + (size_t)(b0 + r) * XROW + c4;
      float4 vp = *reinterpret_cast<const float4*>(xb + fi * ED);
      ushx4 hp;
      hp[0] = f2bf(vp.x); hp[1] = f2bf(vp.y); hp[2] = f2bf(vp.z); hp[3] = f2bf(vp.w);
      *reinterpret_cast<ushx4*>(&Plds[swz(r, c4)]) = hp;
      float4 vq = *reinterpret_cast<const float4*>(xb + fj * ED);
      ushx4 hq;
      hq[0] = f2bf(vq.x); hq[1] = f2bf(vq.y); hq[2] = f2bf(vq.z); hq[3] = f2bf(vq.w);
      *reinterpret_cast<ushx4*>(&Qlds[r * 132 + c4]) = hq;
    }
    __syncthreads();

    // ---- T = P @ K^T via MFMA: wave w owns b-rows w*16..w*16+15, all 128 e ----
    f32x4 acc[8];
    #pragma unroll
    for (int f = 0; f < 8; ++f) acc[f] = (f32x4){0.f, 0.f, 0.f, 0.f};
    #pragma unroll
    for (int kk = 0; kk < 4; ++kk) {
      // A[m][k]: lane holds m=lm, k = lq*8 + j (+32*kk)
      bf16x8 a = *reinterpret_cast<const bf16x8*>(
          &Plds[swz(w * 16 + lm, kk * 32 + lq * 8)]);
      #pragma unroll
      for (int f = 0; f < 8; ++f)
        acc[f] = __builtin_amdgcn_mfma_f32_16x16x32_bf16(a, bfr[kk][f], acc[f], 0, 0, 0);
    }

    // ---- out[b] = sum_e T[b,e] * Q[b,e]; C/D layout: col=lm, row=lq*4+reg ----
    #pragma unroll
    for (int r = 0; r < 4; ++r) {
      const int bl = w * 16 + lq * 4 + r;
      float s = 0.f;
      #pragma unroll
      for (int f = 0; f < 8; ++f)
        s = fmaf(acc[f][r], bf2f(Qlds[bl * 132 + f * 16 + lm]), s);
      s += __shfl_xor(s, 1);
      s += __shfl_xor(s, 2);
      s += __shfl_xor(s, 4);
      s += __shfl_xor(s, 8);
      if (lm == 0) out[(size_t)(b0 + bl) * NIX + n] = s;
    }
  }
}

extern "C" void kernel_launch(void* const* d_in, const int* in_sizes, int n_in,
                              void* d_out, int out_size, void* d_ws, size_t ws_size,
                              hipStream_t stream) {
  const float* x = (const float*)d_in[0];
  const float* kern = (const float*)d_in[1];
  float* out = (float*)d_out;
  (void)in_sizes; (void)n_in; (void)out_size; (void)d_ws; (void)ws_size;
  dim3 grid(NIX, 2, 1);
  opn_kernel<<<grid, 256, 0, stream>>>(x, kern, out);
}

// Round 2
// 76.263 us; speedup vs baseline: 1.2846x; 1.2846x over previous
//
#include <hip/hip_runtime.h>

#define NF 40
#define ED 128
#define NB 1024
#define NIX 780
#define XROW (NF * ED)      // 5120
#define KROW (NIX * ED)     // 99840
#define XB_BYTES (NB * NF * ED * 2)   // 13,107,200
#define KB_BYTES (NIX * ED * ED * 2)  // 25,559,040
#define WS_NEED (XB_BYTES + KB_BYTES)

typedef __attribute__((ext_vector_type(8))) short bf16x8;
typedef __attribute__((ext_vector_type(4))) float f32x4;
typedef __attribute__((ext_vector_type(4))) unsigned short ushx4;
typedef __attribute__((ext_vector_type(8))) unsigned short ushx8;

__device__ __forceinline__ unsigned short f2bf(float x) {
  unsigned int u = __float_as_uint(x);
  u = (u + 0x7FFFu + ((u >> 16) & 1u)) >> 16;
  return (unsigned short)u;
}
__device__ __forceinline__ float bf2f(unsigned short h) {
  return __uint_as_float(((unsigned int)h) << 16);
}

#define GLOAD16(gsrc, ldst)                                                    \
  __builtin_amdgcn_global_load_lds(                                            \
      (const __attribute__((address_space(1))) void*)(gsrc),                   \
      (__attribute__((address_space(3))) void*)(ldst), 16, 0, 0)

// ---------------- prepass: x fp32 -> bf16 (same layout) ----------------
__global__ void cvt_x(const float* __restrict__ x, unsigned short* __restrict__ xb) {
  const size_t g = ((size_t)blockIdx.x * 256 + threadIdx.x) * 8;
  float4 a = *reinterpret_cast<const float4*>(x + g);
  float4 b = *reinterpret_cast<const float4*>(x + g + 4);
  ushx8 h;
  h[0] = f2bf(a.x); h[1] = f2bf(a.y); h[2] = f2bf(a.z); h[3] = f2bf(a.w);
  h[4] = f2bf(b.x); h[5] = f2bf(b.y); h[6] = f2bf(b.z); h[7] = f2bf(b.w);
  *reinterpret_cast<ushx8*>(xb + g) = h;
}

// ------- prepass: kernel [e][n][d] fp32 -> [n][e][d] bf16 (32KB/pair) -------
__global__ void cvt_k(const float* __restrict__ kr, unsigned short* __restrict__ kb) {
  const size_t g = ((size_t)blockIdx.x * 256 + threadIdx.x) * 4;
  const int d = (int)(g & 127);
  const size_t t = g >> 7;
  const int e = (int)(t & 127);
  const int n = (int)(t >> 7);
  float4 v = *reinterpret_cast<const float4*>(kr + ((size_t)e * NIX + n) * ED + d);
  ushx4 h;
  h[0] = f2bf(v.x); h[1] = f2bf(v.y); h[2] = f2bf(v.z); h[3] = f2bf(v.w);
  *reinterpret_cast<ushx4*>(kb + g) = h;
}

// ---------------- main kernel (ws / bf16 path) ----------------
__launch_bounds__(256, 2)
__global__ void opn_ws(const unsigned short* __restrict__ xb,
                       const unsigned short* __restrict__ kb,
                       float* __restrict__ out) {
  // 32 KB union: K_n first, then overlaid by P (0..8191) + Q (8192..16383)
  __shared__ unsigned short S[128 * 128];
  unsigned short* Klds = S;
  unsigned short* Plds = S;
  unsigned short* Qlds = S + 8192;

  const int n = blockIdx.x;
  const int tid = threadIdx.x;
  const int lane = tid & 63;
  const int w = tid >> 6;
  const int lm = lane & 15;
  const int lq = lane >> 4;
  const int col8 = lm * 8;  // staging column (elements)

  // pair (fi, fj)
  int fi = 0, base = 0;
  while (base + (NF - 1 - fi) <= n) { base += NF - 1 - fi; ++fi; }
  const int fj = fi + 1 + (n - base);

  // ---- stage K_n (contiguous 32KB): linear LDS dest, pre-swizzled source ----
  {
    const unsigned short* ks = kb + (size_t)n * (ED * ED);
    #pragma unroll
    for (int j = 0; j < 8; ++j) {
      const int chunk = j * 4 + w;           // 0..31, 1KB each
      const int r = chunk * 4 + lq;          // 0..127
      const int c = col8 ^ ((r & 7) << 3);
      GLOAD16(ks + r * ED + c, Klds + chunk * 512);
    }
  }
  __syncthreads();

  // ---- hoist K as MFMA A-fragments: A[m=e][k=d], e = f*16+lm, d = kk*32+lq*8+j ----
  bf16x8 afr[4][8];
  #pragma unroll
  for (int kk = 0; kk < 4; ++kk)
    #pragma unroll
    for (int f = 0; f < 8; ++f) {
      const int r = f * 16 + lm;
      afr[kk][f] = *reinterpret_cast<const bf16x8*>(
          &Klds[r * ED + ((kk * 32 + lq * 8) ^ ((r & 7) << 3))]);
    }
  // pin in VGPRs — forbid rematerialization from LDS
  #pragma unroll
  for (int kk = 0; kk < 4; ++kk)
    #pragma unroll
    for (int f = 0; f < 8; ++f)
      asm volatile("" : "+v"(afr[kk][f]));
  __syncthreads();  // hoist reads done before P/Q overwrite K space

  for (int t = 0; t < 8; ++t) {
    const int b0 = blockIdx.y * 512 + t * 64;

    // ---- stage P,Q tiles (16KB each) via global_load_lds ----
    #pragma unroll
    for (int j = 0; j < 4; ++j) {
      const int chunk = j * 4 + w;           // 0..15
      const int r = chunk * 4 + lq;          // 0..63
      const int c = col8 ^ ((r & 7) << 3);
      const size_t xoff = ((size_t)(b0 + r) * NF) * ED + c;
      GLOAD16(xb + xoff + (size_t)fi * ED, Plds + chunk * 512);
      GLOAD16(xb + xoff + (size_t)fj * ED, Qlds + chunk * 512);
    }
    __syncthreads();  // compiler drains vmcnt before barrier -> tiles ready

    // ---- T^T = K @ P^T : D[m=e][col=b], wave w owns b = w*16..w*16+15 ----
    f32x4 acc[8];
    #pragma unroll
    for (int f = 0; f < 8; ++f) acc[f] = (f32x4){0.f, 0.f, 0.f, 0.f};
    const int prow = w * 16 + lm;            // this lane's b row
    #pragma unroll
    for (int kk = 0; kk < 4; ++kk) {
      bf16x8 pfr = *reinterpret_cast<const bf16x8*>(
          &Plds[prow * ED + ((kk * 32 + lq * 8) ^ ((prow & 7) << 3))]);
      #pragma unroll
      for (int f = 0; f < 8; ++f)
        acc[f] = __builtin_amdgcn_mfma_f32_16x16x32_bf16(afr[kk][f], pfr, acc[f], 0, 0, 0);
    }

    // ---- dot over e: lane holds T[e = f*16+lq*4+r][b = prow]; Q read b64 ----
    float s = 0.f;
    #pragma unroll
    for (int f = 0; f < 8; ++f) {
      const int c = (f * 16 + lq * 4) ^ ((prow & 7) << 3);
      ushx4 q4 = *reinterpret_cast<const ushx4*>(&Qlds[prow * ED + c]);
      #pragma unroll
      for (int r = 0; r < 4; ++r)
        s = fmaf(acc[f][r], bf2f(q4[r]), s);
    }
    s += __shfl_xor(s, 16);
    s += __shfl_xor(s, 32);
    if (lane < 16) out[(size_t)(b0 + prow) * NIX + n] = s;
    __syncthreads();  // dot reads done before next tile's staging
  }
}

// ---------------- fallback (proven Round-1 kernel, used when ws too small) ----------------
__device__ __forceinline__ int swz_fb(int row, int col) {
  return row * 128 + (col ^ ((row & 7) << 3));
}

__launch_bounds__(256, 2)
__global__ void opn_fb(const float* __restrict__ x,
                       const float* __restrict__ kern,
                       float* __restrict__ out) {
  __shared__ unsigned short Klds[128 * 128];
  __shared__ unsigned short Plds[64 * 128];
  __shared__ unsigned short Qlds[64 * 132];

  const int n = blockIdx.x;
  const int tid = threadIdx.x;
  const int lane = tid & 63;
  const int w = tid >> 6;
  const int lm = lane & 15;
  const int lq = lane >> 4;

  int fi = 0, base = 0;
  while (base + (NF - 1 - fi) <= n) { base += NF - 1 - fi; ++fi; }
  const int fj = fi + 1 + (n - base);

  {
    const int r8 = tid >> 5;
    const int d0 = (tid & 31) * 4;
    const float* kbp = kern + (size_t)n * ED + d0;
    #pragma unroll
    for (int p = 0; p < 16; ++p) {
      int e = p * 8 + r8;
      float4 v = *reinterpret_cast<const float4*>(kbp + (size_t)e * KROW);
      ushx4 h;
      h[0] = f2bf(v.x); h[1] = f2bf(v.y); h[2] = f2bf(v.z); h[3] = f2bf(v.w);
      *reinterpret_cast<ushx4*>(&Klds[swz_fb(e, d0)]) = h;
    }
  }
  __syncthreads();

  bf16x8 bfr[4][8];
  #pragma unroll
  for (int kk = 0; kk < 4; ++kk)
    #pragma unroll
    for (int f = 0; f < 8; ++f)
      bfr[kk][f] = *reinterpret_cast<const bf16x8*>(
          &Klds[swz_fb(f * 16 + lm, kk * 32 + lq * 8)]);

  const int r8 = tid >> 5;
  const int c4 = (tid & 31) * 4;

  for (int t = 0; t < 8; ++t) {
    const int b0 = blockIdx.y * 512 + t * 64;
    __syncthreads();
    #pragma unroll
    for (int p = 0; p < 8; ++p) {
      int r = p * 8 + r8;
      const float* xbp = x + (size_t)(b0 + r) * XROW + c4;
      float4 vp = *reinterpret_cast<const float4*>(xbp + fi * ED);
      ushx4 hp;
      hp[0] = f2bf(vp.x); hp[1] = f2bf(vp.y); hp[2] = f2bf(vp.z); hp[3] = f2bf(vp.w);
      *reinterpret_cast<ushx4*>(&Plds[swz_fb(r, c4)]) = hp;
      float4 vq = *reinterpret_cast<const float4*>(xbp + fj * ED);
      ushx4 hq;
      hq[0] = f2bf(vq.x); hq[1] = f2bf(vq.y); hq[2] = f2bf(vq.z); hq[3] = f2bf(vq.w);
      *reinterpret_cast<ushx4*>(&Qlds[r * 132 + c4]) = hq;
    }
    __syncthreads();

    f32x4 acc[8];
    #pragma unroll
    for (int f = 0; f < 8; ++f) acc[f] = (f32x4){0.f, 0.f, 0.f, 0.f};
    #pragma unroll
    for (int kk = 0; kk < 4; ++kk) {
      bf16x8 a = *reinterpret_cast<const bf16x8*>(
          &Plds[swz_fb(w * 16 + lm, kk * 32 + lq * 8)]);
      #pragma unroll
      for (int f = 0; f < 8; ++f)
        acc[f] = __builtin_amdgcn_mfma_f32_16x16x32_bf16(a, bfr[kk][f], acc[f], 0, 0, 0);
    }

    #pragma unroll
    for (int r = 0; r < 4; ++r) {
      const int bl = w * 16 + lq * 4 + r;
      float s = 0.f;
      #pragma unroll
      for (int f = 0; f < 8; ++f)
        s = fmaf(acc[f][r], bf2f(Qlds[bl * 132 + f * 16 + lm]), s);
      s += __shfl_xor(s, 1);
      s += __shfl_xor(s, 2);
      s += __shfl_xor(s, 4);
      s += __shfl_xor(s, 8);
      if (lm == 0) out[(size_t)(b0 + bl) * NIX + n] = s;
    }
  }
}

extern "C" void kernel_launch(void* const* d_in, const int* in_sizes, int n_in,
                              void* d_out, int out_size, void* d_ws, size_t ws_size,
                              hipStream_t stream) {
  const float* x = (const float*)d_in[0];
  const float* kern = (const float*)d_in[1];
  float* out = (float*)d_out;
  (void)in_sizes; (void)n_in; (void)out_size;

  if (ws_size >= (size_t)WS_NEED) {
    unsigned short* xb = (unsigned short*)d_ws;
    unsigned short* kbuf = (unsigned short*)((char*)d_ws + XB_BYTES);
    cvt_x<<<2560, 256, 0, stream>>>(x, xb);       // 1024*40*128 / (256*8)
    cvt_k<<<12480, 256, 0, stream>>>(kern, kbuf); // 780*128*128 / (256*4)
    dim3 grid(NIX, 2, 1);
    opn_ws<<<grid, 256, 0, stream>>>(xb, kbuf, out);
  } else {
    dim3 grid(NIX, 2, 1);
    opn_fb<<<grid, 256, 0, stream>>>(x, kern, out);
  }
}

// Round 3
// 68.368 us; speedup vs baseline: 1.4330x; 1.1155x over previous
//
#include <hip/hip_runtime.h>

#define NF 40
#define ED 128
#define NB 1024
#define NIX 780
#define XROW (NF * ED)      // 5120
#define KROW (NIX * ED)     // 99840
#define XB_BYTES (NB * NF * ED * 2)   // 13,107,200
#define KB_BYTES (NIX * ED * ED * 2)  // 25,559,040
#define WS_NEED (XB_BYTES + KB_BYTES)

typedef __attribute__((ext_vector_type(8))) short bf16x8;
typedef __attribute__((ext_vector_type(4))) float f32x4;
typedef __attribute__((ext_vector_type(4))) unsigned short ushx4;
typedef __attribute__((ext_vector_type(8))) unsigned short ushx8;

__device__ __forceinline__ unsigned short f2bf(float x) {
  unsigned int u = __float_as_uint(x);
  u = (u + 0x7FFFu + ((u >> 16) & 1u)) >> 16;
  return (unsigned short)u;
}
__device__ __forceinline__ float bf2f(unsigned short h) {
  return __uint_as_float(((unsigned int)h) << 16);
}

#define GLOAD16(gsrc, ldst)                                                    \
  __builtin_amdgcn_global_load_lds(                                            \
      (const __attribute__((address_space(1))) void*)(gsrc),                   \
      (__attribute__((address_space(3))) void*)(ldst), 16, 0, 0)

// counted waits + raw barrier (T3/T4): loads for the NEXT tile stay in
// flight across the barrier; vmcnt(8) retires exactly the previous tile's
// 8 global_load_lds (+ the prior masked store, which retires first in-order).
#define WAITV(N) asm volatile("s_waitcnt vmcnt(" #N ")" ::: "memory")
#define WAITL0() asm volatile("s_waitcnt lgkmcnt(0)" ::: "memory")
#define BARRIER()                                                              \
  do {                                                                         \
    asm volatile("" ::: "memory");                                             \
    __builtin_amdgcn_s_barrier();                                              \
    asm volatile("" ::: "memory");                                             \
  } while (0)

// ---------------- prepass: x fp32 -> bf16 (same layout) ----------------
__global__ void cvt_x(const float* __restrict__ x, unsigned short* __restrict__ xb) {
  const size_t g = ((size_t)blockIdx.x * 256 + threadIdx.x) * 8;
  float4 a = *reinterpret_cast<const float4*>(x + g);
  float4 b = *reinterpret_cast<const float4*>(x + g + 4);
  ushx8 h;
  h[0] = f2bf(a.x); h[1] = f2bf(a.y); h[2] = f2bf(a.z); h[3] = f2bf(a.w);
  h[4] = f2bf(b.x); h[5] = f2bf(b.y); h[6] = f2bf(b.z); h[7] = f2bf(b.w);
  *reinterpret_cast<ushx8*>(xb + g) = h;
}

// ------- prepass: kernel [e][n][d] fp32 -> [n][e][d] bf16 (32KB/pair) -------
__global__ void cvt_k(const float* __restrict__ kr, unsigned short* __restrict__ kb) {
  const size_t g = ((size_t)blockIdx.x * 256 + threadIdx.x) * 4;
  const int d = (int)(g & 127);
  const size_t t = g >> 7;
  const int e = (int)(t & 127);
  const int n = (int)(t >> 7);
  float4 v = *reinterpret_cast<const float4*>(kr + ((size_t)e * NIX + n) * ED + d);
  ushx4 h;
  h[0] = f2bf(v.x); h[1] = f2bf(v.y); h[2] = f2bf(v.z); h[3] = f2bf(v.w);
  *reinterpret_cast<ushx4*>(kb + g) = h;
}

// ---------------- main kernel (ws / bf16, double-buffered pipeline) ----------------
__launch_bounds__(256, 2)
__global__ void opn_ws(const unsigned short* __restrict__ xb,
                       const unsigned short* __restrict__ kb,
                       float* __restrict__ out) {
  // 64 KB: buf0 = S[0..16383], buf1 = S[16384..32767].
  // Each buf: P in [0..8191], Q in [8192..16383]. K staged into buf1 first,
  // hoisted to registers, then buf1 becomes the odd-tile buffer.
  __shared__ unsigned short S[32768];
  unsigned short* buf0 = S;
  unsigned short* buf1 = S + 16384;

  const int n = blockIdx.x;
  const int tid = threadIdx.x;
  const int lane = tid & 63;
  const int w = tid >> 6;
  const int lm = lane & 15;
  const int lq = lane >> 4;
  const int col8 = lm * 8;

  // pair (fi, fj)
  int fi = 0, base = 0;
  while (base + (NF - 1 - fi) <= n) { base += NF - 1 - fi; ++fi; }
  const int fj = fi + 1 + (n - base);

  const unsigned short* xpi = xb + (size_t)fi * ED;
  const unsigned short* xpj = xb + (size_t)fj * ED;
  const int b0base = blockIdx.y * 512;

  // ---- issue K stage into buf1 (8 loads/thread, 32 KB) ----
  {
    const unsigned short* ks = kb + (size_t)n * (ED * ED);
    #pragma unroll
    for (int j = 0; j < 8; ++j) {
      const int chunk = j * 4 + w;           // 0..31, 1KB each
      const int r = chunk * 4 + lq;          // 0..127
      const int c = col8 ^ ((r & 7) << 3);
      GLOAD16(ks + r * ED + c, buf1 + chunk * 512);
    }
  }

  auto stage_pq = [&](unsigned short* buf, int t) {
    const int b0 = b0base + t * 64;
    #pragma unroll
    for (int j = 0; j < 4; ++j) {
      const int chunk = j * 4 + w;           // 0..15
      const int r = chunk * 4 + lq;          // 0..63
      const int c = col8 ^ ((r & 7) << 3);
      const size_t xoff = (size_t)(b0 + r) * XROW + c;
      GLOAD16(xpi + xoff, buf + chunk * 512);
      GLOAD16(xpj + xoff, buf + 8192 + chunk * 512);
    }
  };

  stage_pq(buf0, 0);   // co-issued with K: outstanding = K(8) + PQ0(8)
  WAITV(8);            // K writes complete (PQ0 may still fly)
  BARRIER();

  // ---- hoist K as MFMA A-fragments: A[m=e][k=d] ----
  bf16x8 afr[4][8];
  #pragma unroll
  for (int kk = 0; kk < 4; ++kk)
    #pragma unroll
    for (int f = 0; f < 8; ++f) {
      const int r = f * 16 + lm;
      afr[kk][f] = *reinterpret_cast<const bf16x8*>(
          &buf1[r * ED + ((kk * 32 + lq * 8) ^ ((r & 7) << 3))]);
    }
  #pragma unroll
  for (int kk = 0; kk < 4; ++kk)
    #pragma unroll
    for (int f = 0; f < 8; ++f)
      asm volatile("" : "+v"(afr[kk][f]));   // pin: forbid remat from LDS
  WAITL0();            // this wave's hoist reads done
  BARRIER();           // all waves done reading buf1 -> it becomes a tile buffer

  auto compute = [&](const unsigned short* buf, int t) {
    const unsigned short* Pl = buf;
    const unsigned short* Ql = buf + 8192;
    const int b0 = b0base + t * 64;
    f32x4 acc[8];
    #pragma unroll
    for (int f = 0; f < 8; ++f) acc[f] = (f32x4){0.f, 0.f, 0.f, 0.f};
    const int prow = w * 16 + lm;
    #pragma unroll
    for (int kk = 0; kk < 4; ++kk) {
      bf16x8 pfr = *reinterpret_cast<const bf16x8*>(
          &Pl[prow * ED + ((kk * 32 + lq * 8) ^ ((prow & 7) << 3))]);
      #pragma unroll
      for (int f = 0; f < 8; ++f)
        acc[f] = __builtin_amdgcn_mfma_f32_16x16x32_bf16(afr[kk][f], pfr, acc[f], 0, 0, 0);
    }
    // dot over e: lane holds T[e = f*16+lq*4+r][b = prow]
    float s = 0.f;
    #pragma unroll
    for (int f = 0; f < 8; ++f) {
      const int c = (f * 16 + lq * 4) ^ ((prow & 7) << 3);
      ushx4 q4 = *reinterpret_cast<const ushx4*>(&Ql[prow * ED + c]);
      #pragma unroll
      for (int r = 0; r < 4; ++r)
        s = fmaf(acc[f][r], bf2f(q4[r]), s);
    }
    s += __shfl_xor(s, 16);
    s += __shfl_xor(s, 32);
    if (lane < 16) out[(size_t)(b0 + prow) * NIX + n] = s;
  };

  // ---- pipelined main loop: even tiles in buf0, odd in buf1 ----
  #pragma unroll 1
  for (int t = 0; t < 6; t += 2) {
    stage_pq(buf1, t + 1);
    WAITV(8);            // tile t (buf0) writes complete
    BARRIER();
    compute(buf0, t);
    BARRIER();           // all reads of buf0 done before next overwrite
    stage_pq(buf0, t + 2);
    WAITV(8);            // tile t+1 (buf1) writes complete
    BARRIER();
    compute(buf1, t + 1);
    BARRIER();
  }
  // tiles 6,7
  stage_pq(buf1, 7);
  WAITV(8);
  BARRIER();
  compute(buf0, 6);
  BARRIER();
  WAITV(0);
  BARRIER();
  compute(buf1, 7);
}

// ---------------- fallback (proven Round-1 kernel, used when ws too small) ----------------
__device__ __forceinline__ int swz_fb(int row, int col) {
  return row * 128 + (col ^ ((row & 7) << 3));
}

__launch_bounds__(256, 2)
__global__ void opn_fb(const float* __restrict__ x,
                       const float* __restrict__ kern,
                       float* __restrict__ out) {
  __shared__ unsigned short Klds[128 * 128];
  __shared__ unsigned short Plds[64 * 128];
  __shared__ unsigned short Qlds[64 * 132];

  const int n = blockIdx.x;
  const int tid = threadIdx.x;
  const int lane = tid & 63;
  const int w = tid >> 6;
  const int lm = lane & 15;
  const int lq = lane >> 4;

  int fi = 0, base = 0;
  while (base + (NF - 1 - fi) <= n) { base += NF - 1 - fi; ++fi; }
  const int fj = fi + 1 + (n - base);

  {
    const int r8 = tid >> 5;
    const int d0 = (tid & 31) * 4;
    const float* kbp = kern + (size_t)n * ED + d0;
    #pragma unroll
    for (int p = 0; p < 16; ++p) {
      int e = p * 8 + r8;
      float4 v = *reinterpret_cast<const float4*>(kbp + (size_t)e * KROW);
      ushx4 h;
      h[0] = f2bf(v.x); h[1] = f2bf(v.y); h[2] = f2bf(v.z); h[3] = f2bf(v.w);
      *reinterpret_cast<ushx4*>(&Klds[swz_fb(e, d0)]) = h;
    }
  }
  __syncthreads();

  bf16x8 bfr[4][8];
  #pragma unroll
  for (int kk = 0; kk < 4; ++kk)
    #pragma unroll
    for (int f = 0; f < 8; ++f)
      bfr[kk][f] = *reinterpret_cast<const bf16x8*>(
          &Klds[swz_fb(f * 16 + lm, kk * 32 + lq * 8)]);

  const int r8 = tid >> 5;
  const int c4 = (tid & 31) * 4;

  for (int t = 0; t < 8; ++t) {
    const int b0 = blockIdx.y * 512 + t * 64;
    __syncthreads();
    #pragma unroll
    for (int p = 0; p < 8; ++p) {
      int r = p * 8 + r8;
      const float* xbp = x + (size_t)(b0 + r) * XROW + c4;
      float4 vp = *reinterpret_cast<const float4*>(xbp + fi * ED);
      ushx4 hp;
      hp[0] = f2bf(vp.x); hp[1] = f2bf(vp.y); hp[2] = f2bf(vp.z); hp[3] = f2bf(vp.w);
      *reinterpret_cast<ushx4*>(&Plds[swz_fb(r, c4)]) = hp;
      float4 vq = *reinterpret_cast<const float4*>(xbp + fj * ED);
      ushx4 hq;
      hq[0] = f2bf(vq.x); hq[1] = f2bf(vq.y); hq[2] = f2bf(vq.z); hq[3] = f2bf(vq.w);
      *reinterpret_cast<ushx4*>(&Qlds[r * 132 + c4]) = hq;
    }
    __syncthreads();

    f32x4 acc[8];
    #pragma unroll
    for (int f = 0; f < 8; ++f) acc[f] = (f32x4){0.f, 0.f, 0.f, 0.f};
    #pragma unroll
    for (int kk = 0; kk < 4; ++kk) {
      bf16x8 a = *reinterpret_cast<const bf16x8*>(
          &Plds[swz_fb(w * 16 + lm, kk * 32 + lq * 8)]);
      #pragma unroll
      for (int f = 0; f < 8; ++f)
        acc[f] = __builtin_amdgcn_mfma_f32_16x16x32_bf16(a, bfr[kk][f], acc[f], 0, 0, 0);
    }

    #pragma unroll
    for (int r = 0; r < 4; ++r) {
      const int bl = w * 16 + lq * 4 + r;
      float s = 0.f;
      #pragma unroll
      for (int f = 0; f < 8; ++f)
        s = fmaf(acc[f][r], bf2f(Qlds[bl * 132 + f * 16 + lm]), s);
      s += __shfl_xor(s, 1);
      s += __shfl_xor(s, 2);
      s += __shfl_xor(s, 4);
      s += __shfl_xor(s, 8);
      if (lm == 0) out[(size_t)(b0 + bl) * NIX + n] = s;
    }
  }
}

extern "C" void kernel_launch(void* const* d_in, const int* in_sizes, int n_in,
                              void* d_out, int out_size, void* d_ws, size_t ws_size,
                              hipStream_t stream) {
  const float* x = (const float*)d_in[0];
  const float* kern = (const float*)d_in[1];
  float* out = (float*)d_out;
  (void)in_sizes; (void)n_in; (void)out_size;

  if (ws_size >= (size_t)WS_NEED) {
    unsigned short* xb = (unsigned short*)d_ws;
    unsigned short* kbuf = (unsigned short*)((char*)d_ws + XB_BYTES);
    cvt_x<<<2560, 256, 0, stream>>>(x, xb);       // 1024*40*128 / (256*8)
    cvt_k<<<12480, 256, 0, stream>>>(kern, kbuf); // 780*128*128 / (256*4)
    dim3 grid(NIX, 2, 1);
    opn_ws<<<grid, 256, 0, stream>>>(xb, kbuf, out);
  } else {
    dim3 grid(NIX, 2, 1);
    opn_fb<<<grid, 256, 0, stream>>>(x, kern, out);
  }
}